// Round 5
// baseline (406.151 us; speedup 1.0000x reference)
//
#include <hip/hip_runtime.h>
#include <math.h>

#define NN 50000
#define NE 400000
#define NREL 3
#define NCH 196   // ceil(NN/256) chunks per relation for the scan
// D = 128, H = 8, Dh = 16

typedef __bf16 bf16x8 __attribute__((ext_vector_type(8)));
typedef float floatx4 __attribute__((ext_vector_type(4)));

// ---- bf16 helpers (raw ushort; RNE encode, shift decode) --------------------
__device__ __forceinline__ unsigned short f2bf(float f) {
  unsigned int u = __float_as_uint(f);
  return (unsigned short)((u + 0x7fffu + ((u >> 16) & 1u)) >> 16);
}

// ---------------- weight prep: Wt[mat][n][k] bf16 (n = output col) -----------
// mats 0-2: layer1 rel 0-2; 3-5: layer2; 6: Wc1. Rows 128-143 (mats 0-5):
// wal/war columns appended so the MFMA's 9th n-tile produces el/er directly.
__global__ __launch_bounds__(256) void prep_wt(
    const float* __restrict__ W1, const float* __restrict__ W2,
    const float* __restrict__ Wc1, unsigned short* __restrict__ Wt) {
  int mat = blockIdx.x >> 3, slab = blockIdx.x & 7;
  const float* Wsrc = mat < 3 ? W1 + mat * 16384
                    : (mat < 6 ? W2 + (mat - 3) * 16384 : Wc1);
  unsigned short* dst = Wt + (size_t)mat * 144 * 128;
  int k0 = slab * 16;
#pragma unroll
  for (int i = 0; i < 8; ++i) {
    int idx = i * 256 + threadIdx.x;      // 0..2047
    int k = k0 + (idx >> 7), nn = idx & 127;
    dst[nn * 128 + k] = f2bf(Wsrc[k * 128 + nn]);
  }
}

// wal[k][h] = sum_d W[k][h*16+d]*al[h*16+d]  -> Wt rows 128+h (el) / 136+h (er)
__global__ __launch_bounds__(256) void prep_attn(
    const float* __restrict__ W1, const float* __restrict__ W2,
    const float* __restrict__ al1, const float* __restrict__ ar1,
    const float* __restrict__ al2, const float* __restrict__ ar2,
    unsigned short* __restrict__ Wt) {
  int mat = blockIdx.x;   // 0..5
  const float* Wsrc = mat < 3 ? W1 + mat * 16384 : W2 + (mat - 3) * 16384;
  const float* alp = mat < 3 ? al1 + mat * 128 : al2 + (mat - 3) * 128;
  const float* arp = mat < 3 ? ar1 + mat * 128 : ar2 + (mat - 3) * 128;
  unsigned short* dst = Wt + (size_t)mat * 144 * 128;
#pragma unroll
  for (int i = 0; i < 8; ++i) {
    int j = i * 256 + threadIdx.x;        // 0..2047
    int half = j >> 10, jj = j & 1023;
    int k = jj >> 3, h = jj & 7;
    const float* av = half ? arp : alp;
    float s = 0.f;
#pragma unroll
    for (int d = 0; d < 16; ++d) s += Wsrc[k * 128 + h * 16 + d] * av[h * 16 + d];
    dst[(128 + half * 8 + h) * 128 + k] = f2bf(s);
  }
}

// ---------------- fused 3-relation MFMA GEMM + attn coefficients -------------
// v2: 128-row blocks, B-frags straight from L2-resident Wt (no Ws LDS, ONE
// barrier per block). Each wave: 2 m-tiles x 9 n-tiles; B reused for 2 MFMAs.
__global__ __launch_bounds__(256) void gemm3_attn_mfma(
    const float* __restrict__ X, const unsigned short* __restrict__ Wt,
    unsigned short* __restrict__ hp, float* __restrict__ el,
    float* __restrict__ er, int n) {
  __shared__ unsigned short Xs[128 * 136];   // pad 8: bank-friendly
  int t = threadIdx.x;
  int rowbase = blockIdx.x * 128;

  // stage X -> bf16 LDS (128 rows)
  const float4* X4 = (const float4*)X;
#pragma unroll
  for (int i = 0; i < 16; ++i) {
    int v = t + i * 256;                  // 0..4095
    int row = v >> 5, k4 = (v & 31) * 4;
    float4 x = make_float4(0.f, 0.f, 0.f, 0.f);
    if (rowbase + row < n) x = X4[(size_t)(rowbase + row) * 32 + (v & 31)];
    ushort4 p;
    p.x = f2bf(x.x); p.y = f2bf(x.y); p.z = f2bf(x.z); p.w = f2bf(x.w);
    *(ushort4*)&Xs[row * 136 + k4] = p;
  }
  __syncthreads();

  int lane = t & 63, wave = t >> 6;
  int quad = lane >> 4, l = lane & 15;

  for (int r = 0; r < NREL; ++r) {
    const unsigned short* WtR = Wt + (size_t)r * 144 * 128;

    floatx4 acc[2][9];
#pragma unroll
    for (int mt = 0; mt < 2; ++mt)
#pragma unroll
      for (int i = 0; i < 9; ++i) acc[mt][i] = floatx4{0.f, 0.f, 0.f, 0.f};

#pragma unroll
    for (int ks = 0; ks < 4; ++ks) {
      bf16x8 a0 = *(const bf16x8*)&Xs[(wave * 32 + l) * 136 + ks * 32 + quad * 8];
      bf16x8 a1 = *(const bf16x8*)&Xs[(wave * 32 + 16 + l) * 136 + ks * 32 + quad * 8];
#pragma unroll
      for (int nt = 0; nt < 9; ++nt) {
        bf16x8 b = *(const bf16x8*)&WtR[(size_t)(nt * 16 + l) * 128 + ks * 32 + quad * 8];
        acc[0][nt] = __builtin_amdgcn_mfma_f32_16x16x32_bf16(a0, b, acc[0][nt], 0, 0, 0);
        acc[1][nt] = __builtin_amdgcn_mfma_f32_16x16x32_bf16(a1, b, acc[1][nt], 0, 0, 0);
      }
    }

    unsigned short* hpR = hp + (size_t)r * NN * 128;
    float* elR = el + (size_t)r * NN * 8;
    float* erR = er + (size_t)r * NN * 8;
#pragma unroll
    for (int mt = 0; mt < 2; ++mt) {
      int r0 = rowbase + wave * 32 + mt * 16 + quad * 4;
#pragma unroll
      for (int reg = 0; reg < 4; ++reg) {
        int row = r0 + reg;
        if (row < n) {
#pragma unroll
          for (int nt = 0; nt < 8; ++nt)
            hpR[(size_t)row * 128 + nt * 16 + l] = f2bf(acc[mt][nt][reg]);
          if (l < 8) elR[row * 8 + l] = acc[mt][8][reg];
          else       erR[row * 8 + (l - 8)] = acc[mt][8][reg];
        }
      }
    }
  }
}

// ---------------- head GEMM + fused classifier -------------------------------
// out[row] = relu(X@Wc1 + bc1) . Wc2 + bc2
__global__ __launch_bounds__(256) void gemm_head_mfma(
    const float* __restrict__ X, const unsigned short* __restrict__ Wt,
    const float* __restrict__ bc1, const float* __restrict__ wc2,
    const float* __restrict__ bc2, float* __restrict__ out, int n) {
  __shared__ unsigned short Xs[64 * 136];
  __shared__ unsigned short Ws[128 * 136];
  int t = threadIdx.x;
  int rowbase = blockIdx.x * 64;

  const float4* X4 = (const float4*)X;
#pragma unroll
  for (int i = 0; i < 8; ++i) {
    int v = t + i * 256;
    int row = v >> 5, k4 = (v & 31) * 4;
    float4 x = make_float4(0.f, 0.f, 0.f, 0.f);
    if (rowbase + row < n) x = X4[(size_t)(rowbase + row) * 32 + (v & 31)];
    ushort4 p;
    p.x = f2bf(x.x); p.y = f2bf(x.y); p.z = f2bf(x.z); p.w = f2bf(x.w);
    *(ushort4*)&Xs[row * 136 + k4] = p;
  }
  const uint4* WtR = (const uint4*)Wt;
#pragma unroll
  for (int i = 0; i < 8; ++i) {
    int v = t + i * 256;                  // 0..2047
    ((uint4*)Ws)[(v >> 4) * 17 + (v & 15)] = WtR[v];
  }
  __syncthreads();

  int lane = t & 63, wave = t >> 6;
  int quad = lane >> 4, l = lane & 15;

  floatx4 acc[8];
#pragma unroll
  for (int i = 0; i < 8; ++i) acc[i] = floatx4{0.f, 0.f, 0.f, 0.f};
#pragma unroll
  for (int ks = 0; ks < 4; ++ks) {
    bf16x8 a = *(const bf16x8*)&Xs[(wave * 16 + l) * 136 + ks * 32 + quad * 8];
#pragma unroll
    for (int nt = 0; nt < 8; ++nt) {
      bf16x8 b = *(const bf16x8*)&Ws[(nt * 16 + l) * 136 + ks * 32 + quad * 8];
      acc[nt] = __builtin_amdgcn_mfma_f32_16x16x32_bf16(a, b, acc[nt], 0, 0, 0);
    }
  }

  float bv[8], wv[8];
#pragma unroll
  for (int nt = 0; nt < 8; ++nt) {
    bv[nt] = bc1[nt * 16 + l];
    wv[nt] = wc2[nt * 16 + l];
  }
  int r0 = rowbase + wave * 16 + quad * 4;
#pragma unroll
  for (int reg = 0; reg < 4; ++reg) {
    float s = 0.f;
#pragma unroll
    for (int nt = 0; nt < 8; ++nt)
      s += fmaxf(acc[nt][reg] + bv[nt], 0.f) * wv[nt];
    s += __shfl_xor(s, 1); s += __shfl_xor(s, 2);
    s += __shfl_xor(s, 4); s += __shfl_xor(s, 8);
    int row = r0 + reg;
    if (l == 0 && row < n) out[row] = s + bc2[0];
  }
}

// ---------------- CSR build (rank trick: no atomic in scatter) ---------------
__global__ __launch_bounds__(256) void hist_kernel(
    const int* __restrict__ edst, int* __restrict__ cnt, int* __restrict__ rank) {
  int t = blockIdx.x * 256 + threadIdx.x;
  if (t >= NREL * NE) return;
  int r = t / NE;
  rank[t] = atomicAdd(&cnt[r * NN + edst[t]], 1);
}

__global__ __launch_bounds__(256) void scan1(
    const int* __restrict__ cnt, int* __restrict__ partials) {
  __shared__ int s[256];
  int r = blockIdx.x / NCH, c = blockIdx.x % NCH;
  int i = c * 256 + threadIdx.x;
  s[threadIdx.x] = (i < NN) ? cnt[r * NN + i] : 0;
  __syncthreads();
  for (int off = 128; off; off >>= 1) {
    if (threadIdx.x < off) s[threadIdx.x] += s[threadIdx.x + off];
    __syncthreads();
  }
  if (threadIdx.x == 0) partials[r * NCH + c] = s[0];
}

__global__ __launch_bounds__(256) void scan2(int* __restrict__ partials) {
  __shared__ int s[256];
  int r = blockIdx.x;
  int t = threadIdx.x;
  int v = (t < NCH) ? partials[r * NCH + t] : 0;
  s[t] = v;
  __syncthreads();
  for (int off = 1; off < 256; off <<= 1) {
    int x = (t >= off) ? s[t - off] : 0;
    __syncthreads();
    s[t] += x;
    __syncthreads();
  }
  if (t < NCH) partials[r * NCH + t] = s[t] - v;  // exclusive
}

__global__ __launch_bounds__(256) void scan3(
    const int* __restrict__ cnt, const int* __restrict__ partials,
    int* __restrict__ rowptr) {
  __shared__ int s[256];
  int r = blockIdx.x / NCH, c = blockIdx.x % NCH;
  int t = threadIdx.x;
  int i = c * 256 + t;
  int v = (i < NN) ? cnt[r * NN + i] : 0;
  s[t] = v;
  __syncthreads();
  for (int off = 1; off < 256; off <<= 1) {
    int x = (t >= off) ? s[t - off] : 0;
    __syncthreads();
    s[t] += x;
    __syncthreads();
  }
  int base = partials[r * NCH + c];
  if (i < NN) rowptr[r * (NN + 1) + i] = base + s[t] - v;
  if (c == NCH - 1 && t == 0) rowptr[r * (NN + 1) + NN] = NE;
}

__global__ __launch_bounds__(256) void scatter_kernel(
    const int* __restrict__ esrc, const int* __restrict__ edst,
    const int* __restrict__ rowptr, const int* __restrict__ rank,
    int* __restrict__ col) {
  int t = blockIdx.x * 256 + threadIdx.x;
  if (t >= NREL * NE) return;
  int r = t / NE;
  int pos = rowptr[r * (NN + 1) + edst[t]] + rank[t];
  col[(size_t)r * NE + pos] = esrc[t];
}

// ---------------- fused 3-relation gather + layer tail -----------------------
// R2 structure (best measured): lane split per 8-edge chunk, one distinct
// exp per lane, ds_swizzle redistribution, readlane'd SGPR hp base.
__global__ __launch_bounds__(256) void gather_all(
    const int* __restrict__ rowptr, const int* __restrict__ col,
    const float* __restrict__ el, const float* __restrict__ er,
    const unsigned short* __restrict__ hp, const float* __restrict__ b,
    float* __restrict__ h1, const float* __restrict__ g,
    const float* __restrict__ beta, int mode) {
  int wid = (blockIdx.x * 256 + threadIdx.x) >> 6;
  int lane = threadIdx.x & 63;
  if (wid >= NN) return;
  int h = lane >> 3;    // alpha-phase head; equals channel-head (c>>4)
  int eoff = lane & 7;  // alpha-phase edge slot within chunk
  int c = lane * 2;     // channel pair owned in accumulation

  int st3[NREL], en3[NREL], cv3[NREL];
  float er3[NREL];
#pragma unroll
  for (int r = 0; r < NREL; ++r) {
    const int* rp = rowptr + r * (NN + 1);
    st3[r] = rp[wid];
    en3[r] = rp[wid + 1];
    er3[r] = er[(size_t)r * NN * 8 + wid * 8 + h];
  }
#pragma unroll
  for (int r = 0; r < NREL; ++r) {
    int last = en3[r] - 1;
    last = last < st3[r] ? st3[r] : last;   // empty row: dummy in-bounds load
    int i0 = st3[r] + eoff;
    cv3[r] = col[r * NE + (i0 < last ? i0 : last)];
  }

  float ax = 0.f, ay = 0.f;
#pragma unroll
  for (int r = 0; r < NREL; ++r) {
    int start = st3[r], end = en3[r];
    if (end > start) {
      const int* cl = col + r * NE;
      const float* elr = el + (size_t)r * NN * 8;
      const unsigned short* hpr = hp + (size_t)r * NN * 128;
      float er_me = er3[r];
      int last = end - 1;
      int idx = start + eoff;
      int colv = cv3[r];
      float den = 0.f, sx = 0.f, sy = 0.f;
      for (int i = start; i < end; i += 8) {
        int nidx = idx + 8;
        int colm = cl[nidx < last ? nidx : last];   // prefetch next chunk
        // one distinct (edge,head) per lane
        float e = elr[colv * 8 + h] + er_me;
        e = fmaxf(e, 0.2f * e);
        float x = (idx < end) ? __expf(e) : 0.f;
        den += x;
        unsigned int xi = __float_as_uint(x);
#define GATHER_EDGE(JJ)                                                        \
        {                                                                      \
          int sj = __builtin_amdgcn_readlane(colv, JJ);                        \
          const unsigned int* rowp = (const unsigned int*)(hpr + (size_t)sj * 128); \
          unsigned int u = rowp[lane];                                         \
          float xe = __uint_as_float(                                          \
              __builtin_amdgcn_ds_swizzle(xi, ((JJ) << 5) | 0x18));            \
          sx += xe * __uint_as_float(u << 16);                                 \
          sy += xe * __uint_as_float(u & 0xffff0000u);                         \
        }
        GATHER_EDGE(0)
        GATHER_EDGE(1)
        GATHER_EDGE(2)
        GATHER_EDGE(3)
        GATHER_EDGE(4)
        GATHER_EDGE(5)
        GATHER_EDGE(6)
        GATHER_EDGE(7)
#undef GATHER_EDGE
        idx = nidx;
        colv = colm;
      }
      // sum den over the 8 edge-slot lanes of each head group
      den += __shfl_xor(den, 1);
      den += __shfl_xor(den, 2);
      den += __shfl_xor(den, 4);
      float inv = 1.f / den;
      ax += sx * inv;
      ay += sy * inv;
    }
  }

  float bx = b[c] + b[128 + c] + b[256 + c];
  float by = b[c + 1] + b[128 + c + 1] + b[256 + c + 1];
  float2* hptr = (float2*)&h1[(size_t)wid * 128 + c];
  if (mode == 0) {
    *hptr = make_float2(fmaxf(ax + bx, 0.f), fmaxf(ay + by, 0.f));
  } else {
    float2 r1 = *hptr;
    float vx = ax + bx + r1.x;
    float vy = ay + by + r1.y;
    float s = vx + vy;
#pragma unroll
    for (int off = 32; off; off >>= 1) s += __shfl_xor(s, off);
    float mu = s * (1.f / 128.f);
    float dx = vx - mu, dy = vy - mu;
    float sq = dx * dx + dy * dy;
#pragma unroll
    for (int off = 32; off; off >>= 1) sq += __shfl_xor(sq, off);
    float rstd = rsqrtf(sq * (1.f / 128.f) + 1e-5f);
    *hptr = make_float2(dx * rstd * g[c] + beta[c],
                        dy * rstd * g[c + 1] + beta[c + 1]);
  }
}

extern "C" void kernel_launch(void* const* d_in, const int* in_sizes, int n_in,
                              void* d_out, int out_size, void* d_ws, size_t ws_size,
                              hipStream_t stream) {
  const float* feat = (const float*)d_in[0];
  const int* esrc = (const int*)d_in[1];
  const int* edst = (const int*)d_in[2];
  const float* W1 = (const float*)d_in[3];
  const float* al1 = (const float*)d_in[4];
  const float* ar1 = (const float*)d_in[5];
  const float* b1 = (const float*)d_in[6];
  const float* W2 = (const float*)d_in[7];
  const float* al2 = (const float*)d_in[8];
  const float* ar2 = (const float*)d_in[9];
  const float* b2 = (const float*)d_in[10];
  const float* lng = (const float*)d_in[11];
  const float* lnb = (const float*)d_in[12];
  const float* Wc1 = (const float*)d_in[13];
  const float* bc1 = (const float*)d_in[14];
  const float* Wc2 = (const float*)d_in[15];
  const float* bc2 = (const float*)d_in[16];
  float* out = (float*)d_out;

  // workspace layout
  unsigned short* hp = (unsigned short*)d_ws;            // 3*NN*128 bf16
  float* el = (float*)(hp + (size_t)3 * NN * 128);       // 3*NN*8 f32
  float* er = el + (size_t)3 * NN * 8;                   // 3*NN*8 f32
  float* h1 = er + (size_t)3 * NN * 8;                   // NN*128 f32
  int* rowptr = (int*)(h1 + (size_t)NN * 128);           // 3*(NN+1)
  int* col = rowptr + NREL * (NN + 1);                   // 3*NE
  int* cnt = col + (size_t)NREL * NE;                    // 3*NN
  int* partials = cnt + NREL * NN;                       // 3*NCH
  unsigned short* Wt = (unsigned short*)(((uintptr_t)(partials + NREL * NCH) + 15)
                                         & ~(uintptr_t)15);  // 7*144*128 bf16
  int* rank = (int*)el;  // alias: rank (3*NE) dead before first el write

  const int gemm3_grid = (NN + 127) / 128;       // 391
  const int head_grid = (NN + 63) / 64;          // 782
  const int edge_grid = (NREL * NE + 255) / 256; // 4688
  const int gg_grid = (NN * 64) / 256;           // 12500 (wave per dst)

  // --- weight prep (bf16 transpose + fused wal/war columns) ---
  prep_wt<<<56, 256, 0, stream>>>(W1, W2, Wc1, Wt);
  prep_attn<<<6, 256, 0, stream>>>(W1, W2, al1, ar1, al2, ar2, Wt);

  // --- CSR build (edges shared by both layers) ---
  (void)hipMemsetAsync(cnt, 0, (size_t)NREL * NN * sizeof(int), stream);
  hist_kernel<<<edge_grid, 256, 0, stream>>>(edst, cnt, rank);
  scan1<<<NREL * NCH, 256, 0, stream>>>(cnt, partials);
  scan2<<<NREL, 256, 0, stream>>>(partials);
  scan3<<<NREL * NCH, 256, 0, stream>>>(cnt, partials, rowptr);
  scatter_kernel<<<edge_grid, 256, 0, stream>>>(esrc, edst, rowptr, rank, col);

  // --- layer 1 ---
  gemm3_attn_mfma<<<gemm3_grid, 256, 0, stream>>>(feat, Wt, hp, el, er, NN);
  gather_all<<<gg_grid, 256, 0, stream>>>(rowptr, col, el, er, hp, b1,
                                          h1, nullptr, nullptr, 0);
  // --- layer 2 ---
  gemm3_attn_mfma<<<gemm3_grid, 256, 0, stream>>>(
      h1, Wt + (size_t)3 * 144 * 128, hp, el, er, NN);
  gather_all<<<gg_grid, 256, 0, stream>>>(rowptr, col, el, er, hp, b2,
                                          h1, lng, lnb, 1);
  // --- classifier head ---
  gemm_head_mfma<<<head_grid, 256, 0, stream>>>(
      h1, Wt + (size_t)6 * 144 * 128, bc1, Wc2, bc2, out, NN);
}

// Round 6
// 370.177 us; speedup vs baseline: 1.0972x; 1.0972x over previous
//
#include <hip/hip_runtime.h>
#include <math.h>

#define NN 50000
#define NE 400000
#define NREL 3
#define NCH 196   // ceil(NN/256) chunks per relation for the scan
// D = 128, H = 8, Dh = 16

typedef __bf16 bf16x8 __attribute__((ext_vector_type(8)));
typedef float floatx4 __attribute__((ext_vector_type(4)));

// ---- bf16 helpers (raw ushort; RNE encode, shift decode) --------------------
__device__ __forceinline__ unsigned short f2bf(float f) {
  unsigned int u = __float_as_uint(f);
  return (unsigned short)((u + 0x7fffu + ((u >> 16) & 1u)) >> 16);
}

// ---------------- weight prep: Wt[mat][n][k] bf16 (n = output col) -----------
// mats 0-2: layer1 rel 0-2; 3-5: layer2; 6: Wc1. Rows 128-143 (mats 0-5):
// wal/war columns appended so the MFMA's 9th n-tile produces el/er directly.
__global__ __launch_bounds__(256) void prep_wt(
    const float* __restrict__ W1, const float* __restrict__ W2,
    const float* __restrict__ Wc1, unsigned short* __restrict__ Wt) {
  int mat = blockIdx.x >> 3, slab = blockIdx.x & 7;
  const float* Wsrc = mat < 3 ? W1 + mat * 16384
                    : (mat < 6 ? W2 + (mat - 3) * 16384 : Wc1);
  unsigned short* dst = Wt + (size_t)mat * 144 * 128;
  int k0 = slab * 16;
#pragma unroll
  for (int i = 0; i < 8; ++i) {
    int idx = i * 256 + threadIdx.x;      // 0..2047
    int k = k0 + (idx >> 7), nn = idx & 127;
    dst[nn * 128 + k] = f2bf(Wsrc[k * 128 + nn]);
  }
}

// wal[k][h] = sum_d W[k][h*16+d]*al[h*16+d]  -> Wt rows 128+h (el) / 136+h (er)
__global__ __launch_bounds__(256) void prep_attn(
    const float* __restrict__ W1, const float* __restrict__ W2,
    const float* __restrict__ al1, const float* __restrict__ ar1,
    const float* __restrict__ al2, const float* __restrict__ ar2,
    unsigned short* __restrict__ Wt) {
  int mat = blockIdx.x;   // 0..5
  const float* Wsrc = mat < 3 ? W1 + mat * 16384 : W2 + (mat - 3) * 16384;
  const float* alp = mat < 3 ? al1 + mat * 128 : al2 + (mat - 3) * 128;
  const float* arp = mat < 3 ? ar1 + mat * 128 : ar2 + (mat - 3) * 128;
  unsigned short* dst = Wt + (size_t)mat * 144 * 128;
#pragma unroll
  for (int i = 0; i < 8; ++i) {
    int j = i * 256 + threadIdx.x;        // 0..2047
    int half = j >> 10, jj = j & 1023;
    int k = jj >> 3, h = jj & 7;
    const float* av = half ? arp : alp;
    float s = 0.f;
#pragma unroll
    for (int d = 0; d < 16; ++d) s += Wsrc[k * 128 + h * 16 + d] * av[h * 16 + d];
    dst[(128 + half * 8 + h) * 128 + k] = f2bf(s);
  }
}

// ---------------- fused 3-relation MFMA GEMM + attn coefficients -------------
// v3: 128-row blocks (v2's tiling) + LDS-staged Ws (R2's proven B path).
// Per ks-step: 2 A-frags + 9 B-frags = 44 ds_reads feed 72 MFMAs (2 m-tiles
// reuse each B). Ws staging traffic & barriers per row are half of R2's.
__global__ __launch_bounds__(256) void gemm3_attn_mfma(
    const float* __restrict__ X, const unsigned short* __restrict__ Wt,
    unsigned short* __restrict__ hp, float* __restrict__ el,
    float* __restrict__ er, int n) {
  __shared__ unsigned short Xs[128 * 136];   // pad 8: bank-friendly
  __shared__ unsigned short Ws[144 * 136];
  int t = threadIdx.x;
  int rowbase = blockIdx.x * 128;

  // stage X -> bf16 LDS (128 rows)
  const float4* X4 = (const float4*)X;
#pragma unroll
  for (int i = 0; i < 16; ++i) {
    int v = t + i * 256;                  // 0..4095
    int row = v >> 5, k4 = (v & 31) * 4;
    float4 x = make_float4(0.f, 0.f, 0.f, 0.f);
    if (rowbase + row < n) x = X4[(size_t)(rowbase + row) * 32 + (v & 31)];
    ushort4 p;
    p.x = f2bf(x.x); p.y = f2bf(x.y); p.z = f2bf(x.z); p.w = f2bf(x.w);
    *(ushort4*)&Xs[row * 136 + k4] = p;
  }

  int lane = t & 63, wave = t >> 6;
  int quad = lane >> 4, l = lane & 15;

  for (int r = 0; r < NREL; ++r) {
    __syncthreads();                      // Xs ready / prior Ws readers done
    const uint4* WtR = (const uint4*)(Wt + (size_t)r * 144 * 128);
#pragma unroll
    for (int i = 0; i < 9; ++i) {
      int v = t + i * 256;                // 0..2303
      ((uint4*)Ws)[(v >> 4) * 17 + (v & 15)] = WtR[v];
    }
    __syncthreads();

    floatx4 acc[2][9];
#pragma unroll
    for (int mt = 0; mt < 2; ++mt)
#pragma unroll
      for (int i = 0; i < 9; ++i) acc[mt][i] = floatx4{0.f, 0.f, 0.f, 0.f};

#pragma unroll
    for (int ks = 0; ks < 4; ++ks) {
      bf16x8 a0 = *(const bf16x8*)&Xs[(wave * 32 + l) * 136 + ks * 32 + quad * 8];
      bf16x8 a1 = *(const bf16x8*)&Xs[(wave * 32 + 16 + l) * 136 + ks * 32 + quad * 8];
#pragma unroll
      for (int nt = 0; nt < 9; ++nt) {
        bf16x8 b = *(const bf16x8*)&Ws[(nt * 16 + l) * 136 + ks * 32 + quad * 8];
        acc[0][nt] = __builtin_amdgcn_mfma_f32_16x16x32_bf16(a0, b, acc[0][nt], 0, 0, 0);
        acc[1][nt] = __builtin_amdgcn_mfma_f32_16x16x32_bf16(a1, b, acc[1][nt], 0, 0, 0);
      }
    }

    unsigned short* hpR = hp + (size_t)r * NN * 128;
    float* elR = el + (size_t)r * NN * 8;
    float* erR = er + (size_t)r * NN * 8;
#pragma unroll
    for (int mt = 0; mt < 2; ++mt) {
      int r0 = rowbase + wave * 32 + mt * 16 + quad * 4;
#pragma unroll
      for (int reg = 0; reg < 4; ++reg) {
        int row = r0 + reg;
        if (row < n) {
#pragma unroll
          for (int nt = 0; nt < 8; ++nt)
            hpR[(size_t)row * 128 + nt * 16 + l] = f2bf(acc[mt][nt][reg]);
          if (l < 8) elR[row * 8 + l] = acc[mt][8][reg];
          else       erR[row * 8 + (l - 8)] = acc[mt][8][reg];
        }
      }
    }
  }
}

// ---------------- head GEMM + fused classifier -------------------------------
// out[row] = relu(X@Wc1 + bc1) . Wc2 + bc2
__global__ __launch_bounds__(256) void gemm_head_mfma(
    const float* __restrict__ X, const unsigned short* __restrict__ Wt,
    const float* __restrict__ bc1, const float* __restrict__ wc2,
    const float* __restrict__ bc2, float* __restrict__ out, int n) {
  __shared__ unsigned short Xs[64 * 136];
  __shared__ unsigned short Ws[128 * 136];
  int t = threadIdx.x;
  int rowbase = blockIdx.x * 64;

  const float4* X4 = (const float4*)X;
#pragma unroll
  for (int i = 0; i < 8; ++i) {
    int v = t + i * 256;
    int row = v >> 5, k4 = (v & 31) * 4;
    float4 x = make_float4(0.f, 0.f, 0.f, 0.f);
    if (rowbase + row < n) x = X4[(size_t)(rowbase + row) * 32 + (v & 31)];
    ushort4 p;
    p.x = f2bf(x.x); p.y = f2bf(x.y); p.z = f2bf(x.z); p.w = f2bf(x.w);
    *(ushort4*)&Xs[row * 136 + k4] = p;
  }
  const uint4* WtR = (const uint4*)Wt;
#pragma unroll
  for (int i = 0; i < 8; ++i) {
    int v = t + i * 256;                  // 0..2047
    ((uint4*)Ws)[(v >> 4) * 17 + (v & 15)] = WtR[v];
  }
  __syncthreads();

  int lane = t & 63, wave = t >> 6;
  int quad = lane >> 4, l = lane & 15;

  floatx4 acc[8];
#pragma unroll
  for (int i = 0; i < 8; ++i) acc[i] = floatx4{0.f, 0.f, 0.f, 0.f};
#pragma unroll
  for (int ks = 0; ks < 4; ++ks) {
    bf16x8 a = *(const bf16x8*)&Xs[(wave * 16 + l) * 136 + ks * 32 + quad * 8];
#pragma unroll
    for (int nt = 0; nt < 8; ++nt) {
      bf16x8 b = *(const bf16x8*)&Ws[(nt * 16 + l) * 136 + ks * 32 + quad * 8];
      acc[nt] = __builtin_amdgcn_mfma_f32_16x16x32_bf16(a, b, acc[nt], 0, 0, 0);
    }
  }

  float bv[8], wv[8];
#pragma unroll
  for (int nt = 0; nt < 8; ++nt) {
    bv[nt] = bc1[nt * 16 + l];
    wv[nt] = wc2[nt * 16 + l];
  }
  int r0 = rowbase + wave * 16 + quad * 4;
#pragma unroll
  for (int reg = 0; reg < 4; ++reg) {
    float s = 0.f;
#pragma unroll
    for (int nt = 0; nt < 8; ++nt)
      s += fmaxf(acc[nt][reg] + bv[nt], 0.f) * wv[nt];
    s += __shfl_xor(s, 1); s += __shfl_xor(s, 2);
    s += __shfl_xor(s, 4); s += __shfl_xor(s, 8);
    int row = r0 + reg;
    if (l == 0 && row < n) out[row] = s + bc2[0];
  }
}

// ---------------- CSR build (rank trick: no atomic in scatter) ---------------
__global__ __launch_bounds__(256) void hist_kernel(
    const int* __restrict__ edst, int* __restrict__ cnt, int* __restrict__ rank) {
  int t = blockIdx.x * 256 + threadIdx.x;
  if (t >= NREL * NE) return;
  int r = t / NE;
  rank[t] = atomicAdd(&cnt[r * NN + edst[t]], 1);
}

__global__ __launch_bounds__(256) void scan1(
    const int* __restrict__ cnt, int* __restrict__ partials) {
  __shared__ int s[256];
  int r = blockIdx.x / NCH, c = blockIdx.x % NCH;
  int i = c * 256 + threadIdx.x;
  s[threadIdx.x] = (i < NN) ? cnt[r * NN + i] : 0;
  __syncthreads();
  for (int off = 128; off; off >>= 1) {
    if (threadIdx.x < off) s[threadIdx.x] += s[threadIdx.x + off];
    __syncthreads();
  }
  if (threadIdx.x == 0) partials[r * NCH + c] = s[0];
}

__global__ __launch_bounds__(256) void scan2(int* __restrict__ partials) {
  __shared__ int s[256];
  int r = blockIdx.x;
  int t = threadIdx.x;
  int v = (t < NCH) ? partials[r * NCH + t] : 0;
  s[t] = v;
  __syncthreads();
  for (int off = 1; off < 256; off <<= 1) {
    int x = (t >= off) ? s[t - off] : 0;
    __syncthreads();
    s[t] += x;
    __syncthreads();
  }
  if (t < NCH) partials[r * NCH + t] = s[t] - v;  // exclusive
}

__global__ __launch_bounds__(256) void scan3(
    const int* __restrict__ cnt, const int* __restrict__ partials,
    int* __restrict__ rowptr) {
  __shared__ int s[256];
  int r = blockIdx.x / NCH, c = blockIdx.x % NCH;
  int t = threadIdx.x;
  int i = c * 256 + t;
  int v = (i < NN) ? cnt[r * NN + i] : 0;
  s[t] = v;
  __syncthreads();
  for (int off = 1; off < 256; off <<= 1) {
    int x = (t >= off) ? s[t - off] : 0;
    __syncthreads();
    s[t] += x;
    __syncthreads();
  }
  int base = partials[r * NCH + c];
  if (i < NN) rowptr[r * (NN + 1) + i] = base + s[t] - v;
  if (c == NCH - 1 && t == 0) rowptr[r * (NN + 1) + NN] = NE;
}

__global__ __launch_bounds__(256) void scatter_kernel(
    const int* __restrict__ esrc, const int* __restrict__ edst,
    const int* __restrict__ rowptr, const int* __restrict__ rank,
    int* __restrict__ col) {
  int t = blockIdx.x * 256 + threadIdx.x;
  if (t >= NREL * NE) return;
  int r = t / NE;
  int pos = rowptr[r * (NN + 1) + edst[t]] + rank[t];
  col[(size_t)r * NE + pos] = esrc[t];
}

// ---------------- fused 3-relation gather + layer tail -----------------------
// R2 structure (best measured): lane split per 8-edge chunk, one distinct
// exp per lane, ds_swizzle redistribution, readlane'd SGPR hp base.
__global__ __launch_bounds__(256) void gather_all(
    const int* __restrict__ rowptr, const int* __restrict__ col,
    const float* __restrict__ el, const float* __restrict__ er,
    const unsigned short* __restrict__ hp, const float* __restrict__ b,
    float* __restrict__ h1, const float* __restrict__ g,
    const float* __restrict__ beta, int mode) {
  int wid = (blockIdx.x * 256 + threadIdx.x) >> 6;
  int lane = threadIdx.x & 63;
  if (wid >= NN) return;
  int h = lane >> 3;    // alpha-phase head; equals channel-head (c>>4)
  int eoff = lane & 7;  // alpha-phase edge slot within chunk
  int c = lane * 2;     // channel pair owned in accumulation

  int st3[NREL], en3[NREL], cv3[NREL];
  float er3[NREL];
#pragma unroll
  for (int r = 0; r < NREL; ++r) {
    const int* rp = rowptr + r * (NN + 1);
    st3[r] = rp[wid];
    en3[r] = rp[wid + 1];
    er3[r] = er[(size_t)r * NN * 8 + wid * 8 + h];
  }
#pragma unroll
  for (int r = 0; r < NREL; ++r) {
    int last = en3[r] - 1;
    last = last < st3[r] ? st3[r] : last;   // empty row: dummy in-bounds load
    int i0 = st3[r] + eoff;
    cv3[r] = col[r * NE + (i0 < last ? i0 : last)];
  }

  float ax = 0.f, ay = 0.f;
#pragma unroll
  for (int r = 0; r < NREL; ++r) {
    int start = st3[r], end = en3[r];
    if (end > start) {
      const int* cl = col + r * NE;
      const float* elr = el + (size_t)r * NN * 8;
      const unsigned short* hpr = hp + (size_t)r * NN * 128;
      float er_me = er3[r];
      int last = end - 1;
      int idx = start + eoff;
      int colv = cv3[r];
      float den = 0.f, sx = 0.f, sy = 0.f;
      for (int i = start; i < end; i += 8) {
        int nidx = idx + 8;
        int colm = cl[nidx < last ? nidx : last];   // prefetch next chunk
        // one distinct (edge,head) per lane
        float e = elr[colv * 8 + h] + er_me;
        e = fmaxf(e, 0.2f * e);
        float x = (idx < end) ? __expf(e) : 0.f;
        den += x;
        unsigned int xi = __float_as_uint(x);
#define GATHER_EDGE(JJ)                                                        \
        {                                                                      \
          int sj = __builtin_amdgcn_readlane(colv, JJ);                        \
          const unsigned int* rowp = (const unsigned int*)(hpr + (size_t)sj * 128); \
          unsigned int u = rowp[lane];                                         \
          float xe = __uint_as_float(                                          \
              __builtin_amdgcn_ds_swizzle(xi, ((JJ) << 5) | 0x18));            \
          sx += xe * __uint_as_float(u << 16);                                 \
          sy += xe * __uint_as_float(u & 0xffff0000u);                         \
        }
        GATHER_EDGE(0)
        GATHER_EDGE(1)
        GATHER_EDGE(2)
        GATHER_EDGE(3)
        GATHER_EDGE(4)
        GATHER_EDGE(5)
        GATHER_EDGE(6)
        GATHER_EDGE(7)
#undef GATHER_EDGE
        idx = nidx;
        colv = colm;
      }
      // sum den over the 8 edge-slot lanes of each head group
      den += __shfl_xor(den, 1);
      den += __shfl_xor(den, 2);
      den += __shfl_xor(den, 4);
      float inv = 1.f / den;
      ax += sx * inv;
      ay += sy * inv;
    }
  }

  float bx = b[c] + b[128 + c] + b[256 + c];
  float by = b[c + 1] + b[128 + c + 1] + b[256 + c + 1];
  float2* hptr = (float2*)&h1[(size_t)wid * 128 + c];
  if (mode == 0) {
    *hptr = make_float2(fmaxf(ax + bx, 0.f), fmaxf(ay + by, 0.f));
  } else {
    float2 r1 = *hptr;
    float vx = ax + bx + r1.x;
    float vy = ay + by + r1.y;
    float s = vx + vy;
#pragma unroll
    for (int off = 32; off; off >>= 1) s += __shfl_xor(s, off);
    float mu = s * (1.f / 128.f);
    float dx = vx - mu, dy = vy - mu;
    float sq = dx * dx + dy * dy;
#pragma unroll
    for (int off = 32; off; off >>= 1) sq += __shfl_xor(sq, off);
    float rstd = rsqrtf(sq * (1.f / 128.f) + 1e-5f);
    *hptr = make_float2(dx * rstd * g[c] + beta[c],
                        dy * rstd * g[c + 1] + beta[c + 1]);
  }
}

extern "C" void kernel_launch(void* const* d_in, const int* in_sizes, int n_in,
                              void* d_out, int out_size, void* d_ws, size_t ws_size,
                              hipStream_t stream) {
  const float* feat = (const float*)d_in[0];
  const int* esrc = (const int*)d_in[1];
  const int* edst = (const int*)d_in[2];
  const float* W1 = (const float*)d_in[3];
  const float* al1 = (const float*)d_in[4];
  const float* ar1 = (const float*)d_in[5];
  const float* b1 = (const float*)d_in[6];
  const float* W2 = (const float*)d_in[7];
  const float* al2 = (const float*)d_in[8];
  const float* ar2 = (const float*)d_in[9];
  const float* b2 = (const float*)d_in[10];
  const float* lng = (const float*)d_in[11];
  const float* lnb = (const float*)d_in[12];
  const float* Wc1 = (const float*)d_in[13];
  const float* bc1 = (const float*)d_in[14];
  const float* Wc2 = (const float*)d_in[15];
  const float* bc2 = (const float*)d_in[16];
  float* out = (float*)d_out;

  // workspace layout
  unsigned short* hp = (unsigned short*)d_ws;            // 3*NN*128 bf16
  float* el = (float*)(hp + (size_t)3 * NN * 128);       // 3*NN*8 f32
  float* er = el + (size_t)3 * NN * 8;                   // 3*NN*8 f32
  float* h1 = er + (size_t)3 * NN * 8;                   // NN*128 f32
  int* rowptr = (int*)(h1 + (size_t)NN * 128);           // 3*(NN+1)
  int* col = rowptr + NREL * (NN + 1);                   // 3*NE
  int* cnt = col + (size_t)NREL * NE;                    // 3*NN
  int* partials = cnt + NREL * NN;                       // 3*NCH
  unsigned short* Wt = (unsigned short*)(((uintptr_t)(partials + NREL * NCH) + 15)
                                         & ~(uintptr_t)15);  // 7*144*128 bf16
  int* rank = (int*)el;  // alias: rank (3*NE) dead before first el write

  const int gemm3_grid = (NN + 127) / 128;       // 391
  const int head_grid = (NN + 63) / 64;          // 782
  const int edge_grid = (NREL * NE + 255) / 256; // 4688
  const int gg_grid = (NN * 64) / 256;           // 12500 (wave per dst)

  // --- weight prep (bf16 transpose + fused wal/war columns) ---
  prep_wt<<<56, 256, 0, stream>>>(W1, W2, Wc1, Wt);
  prep_attn<<<6, 256, 0, stream>>>(W1, W2, al1, ar1, al2, ar2, Wt);

  // --- CSR build (edges shared by both layers) ---
  (void)hipMemsetAsync(cnt, 0, (size_t)NREL * NN * sizeof(int), stream);
  hist_kernel<<<edge_grid, 256, 0, stream>>>(edst, cnt, rank);
  scan1<<<NREL * NCH, 256, 0, stream>>>(cnt, partials);
  scan2<<<NREL, 256, 0, stream>>>(partials);
  scan3<<<NREL * NCH, 256, 0, stream>>>(cnt, partials, rowptr);
  scatter_kernel<<<edge_grid, 256, 0, stream>>>(esrc, edst, rowptr, rank, col);

  // --- layer 1 ---
  gemm3_attn_mfma<<<gemm3_grid, 256, 0, stream>>>(feat, Wt, hp, el, er, NN);
  gather_all<<<gg_grid, 256, 0, stream>>>(rowptr, col, el, er, hp, b1,
                                          h1, nullptr, nullptr, 0);
  // --- layer 2 ---
  gemm3_attn_mfma<<<gemm3_grid, 256, 0, stream>>>(
      h1, Wt + (size_t)3 * 144 * 128, hp, el, er, NN);
  gather_all<<<gg_grid, 256, 0, stream>>>(rowptr, col, el, er, hp, b2,
                                          h1, lng, lnb, 1);
  // --- classifier head ---
  gemm_head_mfma<<<head_grid, 256, 0, stream>>>(
      h1, Wt + (size_t)6 * 144 * 128, bc1, Wc2, bc2, out, NN);
}

// Round 7
// 364.096 us; speedup vs baseline: 1.1155x; 1.0167x over previous
//
#include <hip/hip_runtime.h>
#include <math.h>

#define NN 50000
#define NE 400000
#define NREL 3
#define NCH 196   // ceil(NN/256) chunks per relation for the scan
// D = 128, H = 8, Dh = 16

typedef __bf16 bf16x8 __attribute__((ext_vector_type(8)));
typedef float floatx4 __attribute__((ext_vector_type(4)));

// ---- bf16 helpers (raw ushort; RNE encode, shift decode) --------------------
__device__ __forceinline__ unsigned short f2bf(float f) {
  unsigned int u = __float_as_uint(f);
  return (unsigned short)((u + 0x7fffu + ((u >> 16) & 1u)) >> 16);
}

// ---------------- weight prep: Wt[mat][n][k] bf16 (n = output col) -----------
// mats 0-2: layer1 rel 0-2; 3-5: layer2; 6: Wc1. Rows 128-143 (mats 0-5):
// wal/war columns appended so the MFMA's 9th n-tile produces el/er directly.
// Tail: zero the CSR cnt buffer (replaces hipMemsetAsync; runs before hist).
__global__ __launch_bounds__(256) void prep_wt(
    const float* __restrict__ W1, const float* __restrict__ W2,
    const float* __restrict__ Wc1, unsigned short* __restrict__ Wt,
    int* __restrict__ cnt) {
  int mat = blockIdx.x >> 3, slab = blockIdx.x & 7;
  const float* Wsrc = mat < 3 ? W1 + mat * 16384
                    : (mat < 6 ? W2 + (mat - 3) * 16384 : Wc1);
  unsigned short* dst = Wt + (size_t)mat * 144 * 128;
  int k0 = slab * 16;
#pragma unroll
  for (int i = 0; i < 8; ++i) {
    int idx = i * 256 + threadIdx.x;      // 0..2047
    int k = k0 + (idx >> 7), nn = idx & 127;
    dst[nn * 128 + k] = f2bf(Wsrc[k * 128 + nn]);
  }
  // zero cnt (NREL*NN ints), grid-stride over the 56-block grid
  for (int i = blockIdx.x * 256 + threadIdx.x; i < NREL * NN; i += 56 * 256)
    cnt[i] = 0;
}

// wal[k][h] = sum_d W[k][h*16+d]*al[h*16+d]  -> Wt rows 128+h (el) / 136+h (er)
// v2: 48 blocks = mat(6) x half(2) x kslab(4); one (h,k) per thread, float4.
__global__ __launch_bounds__(256) void prep_attn(
    const float* __restrict__ W1, const float* __restrict__ W2,
    const float* __restrict__ al1, const float* __restrict__ ar1,
    const float* __restrict__ al2, const float* __restrict__ ar2,
    unsigned short* __restrict__ Wt) {
  int blk = blockIdx.x;
  int mat = blk >> 3;             // 0..5
  int half = (blk >> 2) & 1;
  int kslab = blk & 3;
  const float* Wsrc = mat < 3 ? W1 + mat * 16384 : W2 + (mat - 3) * 16384;
  const float* av = half ? (mat < 3 ? ar1 + mat * 128 : ar2 + (mat - 3) * 128)
                         : (mat < 3 ? al1 + mat * 128 : al2 + (mat - 3) * 128);
  int h = threadIdx.x & 7;
  int k = kslab * 32 + (threadIdx.x >> 3);
  float s = 0.f;
#pragma unroll
  for (int j = 0; j < 4; ++j) {
    float4 w = *(const float4*)&Wsrc[k * 128 + h * 16 + j * 4];
    float4 a = *(const float4*)&av[h * 16 + j * 4];
    s += w.x * a.x + w.y * a.y + w.z * a.z + w.w * a.w;
  }
  Wt[(size_t)mat * 144 * 128 + (128 + half * 8 + h) * 128 + k] = f2bf(s);
}

// ---------------- fused 3-relation MFMA GEMM + attn coefficients -------------
// v4: A-fragments loaded ONCE into registers from global X (f32->bf16) and
// reused across all 3 relations; no Xs LDS -> 39.2 KB LDS -> 4 blocks/CU
// (4 waves/SIMD, 2x the latency hiding of the LDS-staged variants).
__global__ __launch_bounds__(256, 4) void gemm3_attn_mfma(
    const float* __restrict__ X, const unsigned short* __restrict__ Wt,
    unsigned short* __restrict__ hp, float* __restrict__ el,
    float* __restrict__ er, int n) {
  __shared__ unsigned short Ws[144 * 136];
  int t = threadIdx.x;
  int lane = t & 63, wave = t >> 6;
  int quad = lane >> 4, l = lane & 15;
  int rowbase = blockIdx.x * 64;
  int myrow = rowbase + wave * 16 + l;

  // A-frags: 4 ks x 8 bf16 per lane, from global, converted once
  bf16x8 afr[4];
  const float4* X4 = (const float4*)X;
#pragma unroll
  for (int ks = 0; ks < 4; ++ks) {
    float4 x0 = make_float4(0.f, 0.f, 0.f, 0.f), x1 = x0;
    if (myrow < n) {
      size_t base = (size_t)myrow * 32 + ks * 8 + quad * 2;
      x0 = X4[base];
      x1 = X4[base + 1];
    }
    union { unsigned short u[8]; bf16x8 v; } cv;
    cv.u[0] = f2bf(x0.x); cv.u[1] = f2bf(x0.y);
    cv.u[2] = f2bf(x0.z); cv.u[3] = f2bf(x0.w);
    cv.u[4] = f2bf(x1.x); cv.u[5] = f2bf(x1.y);
    cv.u[6] = f2bf(x1.z); cv.u[7] = f2bf(x1.w);
    afr[ks] = cv.v;
  }

  for (int r = 0; r < NREL; ++r) {
    if (r > 0) __syncthreads();           // prior Ws readers done
    const uint4* WtR = (const uint4*)(Wt + (size_t)r * 144 * 128);
#pragma unroll
    for (int i = 0; i < 9; ++i) {
      int v = t + i * 256;                // 0..2303
      ((uint4*)Ws)[(v >> 4) * 17 + (v & 15)] = WtR[v];
    }
    __syncthreads();

    floatx4 acc[9];
#pragma unroll
    for (int i = 0; i < 9; ++i) acc[i] = floatx4{0.f, 0.f, 0.f, 0.f};
#pragma unroll
    for (int ks = 0; ks < 4; ++ks) {
#pragma unroll
      for (int nt = 0; nt < 9; ++nt) {
        bf16x8 b = *(const bf16x8*)&Ws[(nt * 16 + l) * 136 + ks * 32 + quad * 8];
        acc[nt] = __builtin_amdgcn_mfma_f32_16x16x32_bf16(afr[ks], b, acc[nt], 0, 0, 0);
      }
    }

    unsigned short* hpR = hp + (size_t)r * NN * 128;
    float* elR = el + (size_t)r * NN * 8;
    float* erR = er + (size_t)r * NN * 8;
    int r0 = rowbase + wave * 16 + quad * 4;
#pragma unroll
    for (int reg = 0; reg < 4; ++reg) {
      int row = r0 + reg;
      if (row < n) {
#pragma unroll
        for (int nt = 0; nt < 8; ++nt)
          hpR[(size_t)row * 128 + nt * 16 + l] = f2bf(acc[nt][reg]);
        if (l < 8) elR[row * 8 + l] = acc[8][reg];
        else       erR[row * 8 + (l - 8)] = acc[8][reg];
      }
    }
  }
}

// ---------------- head GEMM + fused classifier -------------------------------
// out[row] = relu(X@Wc1 + bc1) . Wc2 + bc2
__global__ __launch_bounds__(256) void gemm_head_mfma(
    const float* __restrict__ X, const unsigned short* __restrict__ Wt,
    const float* __restrict__ bc1, const float* __restrict__ wc2,
    const float* __restrict__ bc2, float* __restrict__ out, int n) {
  __shared__ unsigned short Xs[64 * 136];
  __shared__ unsigned short Ws[128 * 136];
  int t = threadIdx.x;
  int rowbase = blockIdx.x * 64;

  const float4* X4 = (const float4*)X;
#pragma unroll
  for (int i = 0; i < 8; ++i) {
    int v = t + i * 256;
    int row = v >> 5, k4 = (v & 31) * 4;
    float4 x = make_float4(0.f, 0.f, 0.f, 0.f);
    if (rowbase + row < n) x = X4[(size_t)(rowbase + row) * 32 + (v & 31)];
    ushort4 p;
    p.x = f2bf(x.x); p.y = f2bf(x.y); p.z = f2bf(x.z); p.w = f2bf(x.w);
    *(ushort4*)&Xs[row * 136 + k4] = p;
  }
  const uint4* WtR = (const uint4*)Wt;
#pragma unroll
  for (int i = 0; i < 8; ++i) {
    int v = t + i * 256;                  // 0..2047
    ((uint4*)Ws)[(v >> 4) * 17 + (v & 15)] = WtR[v];
  }
  __syncthreads();

  int lane = t & 63, wave = t >> 6;
  int quad = lane >> 4, l = lane & 15;

  floatx4 acc[8];
#pragma unroll
  for (int i = 0; i < 8; ++i) acc[i] = floatx4{0.f, 0.f, 0.f, 0.f};
#pragma unroll
  for (int ks = 0; ks < 4; ++ks) {
    bf16x8 a = *(const bf16x8*)&Xs[(wave * 16 + l) * 136 + ks * 32 + quad * 8];
#pragma unroll
    for (int nt = 0; nt < 8; ++nt) {
      bf16x8 b = *(const bf16x8*)&Ws[(nt * 16 + l) * 136 + ks * 32 + quad * 8];
      acc[nt] = __builtin_amdgcn_mfma_f32_16x16x32_bf16(a, b, acc[nt], 0, 0, 0);
    }
  }

  float bv[8], wv[8];
#pragma unroll
  for (int nt = 0; nt < 8; ++nt) {
    bv[nt] = bc1[nt * 16 + l];
    wv[nt] = wc2[nt * 16 + l];
  }
  int r0 = rowbase + wave * 16 + quad * 4;
#pragma unroll
  for (int reg = 0; reg < 4; ++reg) {
    float s = 0.f;
#pragma unroll
    for (int nt = 0; nt < 8; ++nt)
      s += fmaxf(acc[nt][reg] + bv[nt], 0.f) * wv[nt];
    s += __shfl_xor(s, 1); s += __shfl_xor(s, 2);
    s += __shfl_xor(s, 4); s += __shfl_xor(s, 8);
    int row = r0 + reg;
    if (l == 0 && row < n) out[row] = s + bc2[0];
  }
}

// ---------------- CSR build (rank trick: no atomic in scatter) ---------------
// NOTE: rank order (edge index) keeps gather summation order deterministic —
// absmax sits at the 2^-7 threshold, do not perturb summation order.
__global__ __launch_bounds__(256) void hist_kernel(
    const int* __restrict__ edst, int* __restrict__ cnt, int* __restrict__ rank) {
  int t = blockIdx.x * 256 + threadIdx.x;
  if (t >= NREL * NE) return;
  int r = t / NE;
  rank[t] = atomicAdd(&cnt[r * NN + edst[t]], 1);
}

__global__ __launch_bounds__(256) void scan1(
    const int* __restrict__ cnt, int* __restrict__ partials) {
  __shared__ int s[256];
  int r = blockIdx.x / NCH, c = blockIdx.x % NCH;
  int i = c * 256 + threadIdx.x;
  s[threadIdx.x] = (i < NN) ? cnt[r * NN + i] : 0;
  __syncthreads();
  for (int off = 128; off; off >>= 1) {
    if (threadIdx.x < off) s[threadIdx.x] += s[threadIdx.x + off];
    __syncthreads();
  }
  if (threadIdx.x == 0) partials[r * NCH + c] = s[0];
}

__global__ __launch_bounds__(256) void scan2(int* __restrict__ partials) {
  __shared__ int s[256];
  int r = blockIdx.x;
  int t = threadIdx.x;
  int v = (t < NCH) ? partials[r * NCH + t] : 0;
  s[t] = v;
  __syncthreads();
  for (int off = 1; off < 256; off <<= 1) {
    int x = (t >= off) ? s[t - off] : 0;
    __syncthreads();
    s[t] += x;
    __syncthreads();
  }
  if (t < NCH) partials[r * NCH + t] = s[t] - v;  // exclusive
}

__global__ __launch_bounds__(256) void scan3(
    const int* __restrict__ cnt, const int* __restrict__ partials,
    int* __restrict__ rowptr) {
  __shared__ int s[256];
  int r = blockIdx.x / NCH, c = blockIdx.x % NCH;
  int t = threadIdx.x;
  int i = c * 256 + t;
  int v = (i < NN) ? cnt[r * NN + i] : 0;
  s[t] = v;
  __syncthreads();
  for (int off = 1; off < 256; off <<= 1) {
    int x = (t >= off) ? s[t - off] : 0;
    __syncthreads();
    s[t] += x;
    __syncthreads();
  }
  int base = partials[r * NCH + c];
  if (i < NN) rowptr[r * (NN + 1) + i] = base + s[t] - v;
  if (c == NCH - 1 && t == 0) rowptr[r * (NN + 1) + NN] = NE;
}

__global__ __launch_bounds__(256) void scatter_kernel(
    const int* __restrict__ esrc, const int* __restrict__ edst,
    const int* __restrict__ rowptr, const int* __restrict__ rank,
    int* __restrict__ col) {
  int t = blockIdx.x * 256 + threadIdx.x;
  if (t >= NREL * NE) return;
  int r = t / NE;
  int pos = rowptr[r * (NN + 1) + edst[t]] + rank[t];
  col[(size_t)r * NE + pos] = esrc[t];
}

// ---------------- fused 3-relation gather + layer tail -----------------------
// R2 structure (best measured): lane split per 8-edge chunk, one distinct
// exp per lane, ds_swizzle redistribution, readlane'd SGPR hp base.
__global__ __launch_bounds__(256) void gather_all(
    const int* __restrict__ rowptr, const int* __restrict__ col,
    const float* __restrict__ el, const float* __restrict__ er,
    const unsigned short* __restrict__ hp, const float* __restrict__ b,
    float* __restrict__ h1, const float* __restrict__ g,
    const float* __restrict__ beta, int mode) {
  int wid = (blockIdx.x * 256 + threadIdx.x) >> 6;
  int lane = threadIdx.x & 63;
  if (wid >= NN) return;
  int h = lane >> 3;    // alpha-phase head; equals channel-head (c>>4)
  int eoff = lane & 7;  // alpha-phase edge slot within chunk
  int c = lane * 2;     // channel pair owned in accumulation

  int st3[NREL], en3[NREL], cv3[NREL];
  float er3[NREL];
#pragma unroll
  for (int r = 0; r < NREL; ++r) {
    const int* rp = rowptr + r * (NN + 1);
    st3[r] = rp[wid];
    en3[r] = rp[wid + 1];
    er3[r] = er[(size_t)r * NN * 8 + wid * 8 + h];
  }
#pragma unroll
  for (int r = 0; r < NREL; ++r) {
    int last = en3[r] - 1;
    last = last < st3[r] ? st3[r] : last;   // empty row: dummy in-bounds load
    int i0 = st3[r] + eoff;
    cv3[r] = col[r * NE + (i0 < last ? i0 : last)];
  }

  float ax = 0.f, ay = 0.f;
#pragma unroll
  for (int r = 0; r < NREL; ++r) {
    int start = st3[r], end = en3[r];
    if (end > start) {
      const int* cl = col + r * NE;
      const float* elr = el + (size_t)r * NN * 8;
      const unsigned short* hpr = hp + (size_t)r * NN * 128;
      float er_me = er3[r];
      int last = end - 1;
      int idx = start + eoff;
      int colv = cv3[r];
      float den = 0.f, sx = 0.f, sy = 0.f;
      for (int i = start; i < end; i += 8) {
        int nidx = idx + 8;
        int colm = cl[nidx < last ? nidx : last];   // prefetch next chunk
        // one distinct (edge,head) per lane
        float e = elr[colv * 8 + h] + er_me;
        e = fmaxf(e, 0.2f * e);
        float x = (idx < end) ? __expf(e) : 0.f;
        den += x;
        unsigned int xi = __float_as_uint(x);
#define GATHER_EDGE(JJ)                                                        \
        {                                                                      \
          int sj = __builtin_amdgcn_readlane(colv, JJ);                        \
          const unsigned int* rowp = (const unsigned int*)(hpr + (size_t)sj * 128); \
          unsigned int u = rowp[lane];                                         \
          float xe = __uint_as_float(                                          \
              __builtin_amdgcn_ds_swizzle(xi, ((JJ) << 5) | 0x18));            \
          sx += xe * __uint_as_float(u << 16);                                 \
          sy += xe * __uint_as_float(u & 0xffff0000u);                         \
        }
        GATHER_EDGE(0)
        GATHER_EDGE(1)
        GATHER_EDGE(2)
        GATHER_EDGE(3)
        GATHER_EDGE(4)
        GATHER_EDGE(5)
        GATHER_EDGE(6)
        GATHER_EDGE(7)
#undef GATHER_EDGE
        idx = nidx;
        colv = colm;
      }
      // sum den over the 8 edge-slot lanes of each head group
      den += __shfl_xor(den, 1);
      den += __shfl_xor(den, 2);
      den += __shfl_xor(den, 4);
      float inv = 1.f / den;
      ax += sx * inv;
      ay += sy * inv;
    }
  }

  float bx = b[c] + b[128 + c] + b[256 + c];
  float by = b[c + 1] + b[128 + c + 1] + b[256 + c + 1];
  float2* hptr = (float2*)&h1[(size_t)wid * 128 + c];
  if (mode == 0) {
    *hptr = make_float2(fmaxf(ax + bx, 0.f), fmaxf(ay + by, 0.f));
  } else {
    float2 r1 = *hptr;
    float vx = ax + bx + r1.x;
    float vy = ay + by + r1.y;
    float s = vx + vy;
#pragma unroll
    for (int off = 32; off; off >>= 1) s += __shfl_xor(s, off);
    float mu = s * (1.f / 128.f);
    float dx = vx - mu, dy = vy - mu;
    float sq = dx * dx + dy * dy;
#pragma unroll
    for (int off = 32; off; off >>= 1) sq += __shfl_xor(sq, off);
    float rstd = rsqrtf(sq * (1.f / 128.f) + 1e-5f);
    *hptr = make_float2(dx * rstd * g[c] + beta[c],
                        dy * rstd * g[c + 1] + beta[c + 1]);
  }
}

extern "C" void kernel_launch(void* const* d_in, const int* in_sizes, int n_in,
                              void* d_out, int out_size, void* d_ws, size_t ws_size,
                              hipStream_t stream) {
  const float* feat = (const float*)d_in[0];
  const int* esrc = (const int*)d_in[1];
  const int* edst = (const int*)d_in[2];
  const float* W1 = (const float*)d_in[3];
  const float* al1 = (const float*)d_in[4];
  const float* ar1 = (const float*)d_in[5];
  const float* b1 = (const float*)d_in[6];
  const float* W2 = (const float*)d_in[7];
  const float* al2 = (const float*)d_in[8];
  const float* ar2 = (const float*)d_in[9];
  const float* b2 = (const float*)d_in[10];
  const float* lng = (const float*)d_in[11];
  const float* lnb = (const float*)d_in[12];
  const float* Wc1 = (const float*)d_in[13];
  const float* bc1 = (const float*)d_in[14];
  const float* Wc2 = (const float*)d_in[15];
  const float* bc2 = (const float*)d_in[16];
  float* out = (float*)d_out;

  // workspace layout
  unsigned short* hp = (unsigned short*)d_ws;            // 3*NN*128 bf16
  float* el = (float*)(hp + (size_t)3 * NN * 128);       // 3*NN*8 f32
  float* er = el + (size_t)3 * NN * 8;                   // 3*NN*8 f32
  float* h1 = er + (size_t)3 * NN * 8;                   // NN*128 f32
  int* rowptr = (int*)(h1 + (size_t)NN * 128);           // 3*(NN+1)
  int* col = rowptr + NREL * (NN + 1);                   // 3*NE
  int* cnt = col + (size_t)NREL * NE;                    // 3*NN
  int* partials = cnt + NREL * NN;                       // 3*NCH
  unsigned short* Wt = (unsigned short*)(((uintptr_t)(partials + NREL * NCH) + 15)
                                         & ~(uintptr_t)15);  // 7*144*128 bf16
  int* rank = (int*)el;  // alias: rank (3*NE) dead before first el write

  const int gemm3_grid = (NN + 63) / 64;         // 782
  const int head_grid = (NN + 63) / 64;          // 782
  const int edge_grid = (NREL * NE + 255) / 256; // 4688
  const int gg_grid = (NN * 64) / 256;           // 12500 (wave per dst)

  // --- weight prep (bf16 transpose + fused wal/war columns) + cnt zero ---
  prep_wt<<<56, 256, 0, stream>>>(W1, W2, Wc1, Wt, cnt);
  prep_attn<<<48, 256, 0, stream>>>(W1, W2, al1, ar1, al2, ar2, Wt);

  // --- CSR build (edges shared by both layers) ---
  hist_kernel<<<edge_grid, 256, 0, stream>>>(edst, cnt, rank);
  scan1<<<NREL * NCH, 256, 0, stream>>>(cnt, partials);
  scan2<<<NREL, 256, 0, stream>>>(partials);
  scan3<<<NREL * NCH, 256, 0, stream>>>(cnt, partials, rowptr);
  scatter_kernel<<<edge_grid, 256, 0, stream>>>(esrc, edst, rowptr, rank, col);

  // --- layer 1 ---
  gemm3_attn_mfma<<<gemm3_grid, 256, 0, stream>>>(feat, Wt, hp, el, er, NN);
  gather_all<<<gg_grid, 256, 0, stream>>>(rowptr, col, el, er, hp, b1,
                                          h1, nullptr, nullptr, 0);
  // --- layer 2 ---
  gemm3_attn_mfma<<<gemm3_grid, 256, 0, stream>>>(
      h1, Wt + (size_t)3 * 144 * 128, hp, el, er, NN);
  gather_all<<<gg_grid, 256, 0, stream>>>(rowptr, col, el, er, hp, b2,
                                          h1, lng, lnb, 1);
  // --- classifier head ---
  gemm_head_mfma<<<head_grid, 256, 0, stream>>>(
      h1, Wt + (size_t)6 * 144 * 128, bc1, Wc2, bc2, out, NN);
}